// Round 2
// baseline (481.164 us; speedup 1.0000x reference)
//
#include <hip/hip_runtime.h>

#define T_SEQ 2048
#define DMODEL 2048
#define NHEADS 16
#define NKV 4
#define HDIM 128
#define KVDIM (NKV*HDIM)          // 512
#define QKVN (DMODEL + 2*KVDIM)   // 3072

typedef __bf16 bf16x8 __attribute__((ext_vector_type(8)));
typedef float f32x4 __attribute__((ext_vector_type(4)));
typedef unsigned short us8 __attribute__((ext_vector_type(8)));
typedef unsigned short ushort_t;

__device__ __forceinline__ ushort_t f2b(float f) {
    union { float f; unsigned u; } c; c.f = f;
    unsigned r = c.u + 0x7FFFu + ((c.u >> 16) & 1u);
    return (ushort_t)(r >> 16);
}
__device__ __forceinline__ float b2f(ushort_t b) {
    union { unsigned u; float f; } c; c.u = ((unsigned)b) << 16; return c.f;
}

#define GLDS(g, l) __builtin_amdgcn_global_load_lds( \
    (const __attribute__((address_space(1))) void*)(g), \
    (__attribute__((address_space(3))) void*)(l), 16, 0, 0)

// ---------------------------------------------------------------- convert
__global__ __launch_bounds__(256) void cvt_kernel(const float* __restrict__ s,
                                                  ushort_t* __restrict__ d, int n) {
    int i = (blockIdx.x * 256 + threadIdx.x) * 4;
    if (i < n) {
        const float4 v = *(const float4*)(s + i);
        ushort4 o = make_ushort4(f2b(v.x), f2b(v.y), f2b(v.z), f2b(v.w));
        *(ushort4*)(d + i) = o;
    }
}

// ---------------------------------------------------------------- GEMM C = A @ B^T
// A: M x K bf16 row-major, B: N x K bf16 row-major. 128x128 tile, BK=64,
// 256 threads = 4 waves (2x2), each wave 64x64 (4x4 frags of 16x16x32 MFMA).
template<bool F32OUT>
__global__ __launch_bounds__(256) void gemm_bt(
    const ushort_t* __restrict__ A, const ushort_t* __restrict__ B,
    ushort_t* __restrict__ Cb, float* __restrict__ Cf,
    int M, int N, int K)
{
    __shared__ ushort_t As[128 * 64];
    __shared__ ushort_t Bs[128 * 64];
    const int tid = threadIdx.x;
    const int lane = tid & 63;
    const int wv = tid >> 6;
    const int wr = wv >> 1, wc = wv & 1;
    const int lrow = lane & 15, lhi = lane >> 4;
    const int m0 = blockIdx.y * 128, n0 = blockIdx.x * 128;

    f32x4 acc[4][4];
#pragma unroll
    for (int i = 0; i < 4; i++)
#pragma unroll
        for (int j = 0; j < 4; j++) acc[i][j] = f32x4{0.f, 0.f, 0.f, 0.f};

    const int srow = tid >> 3;          // 0..31
    const int scol = (tid & 7) * 8;     // 0..56

    for (int kt = 0; kt < K; kt += 64) {
        if (kt) __syncthreads();
#pragma unroll
        for (int r = 0; r < 4; ++r) {
            int row = srow + r * 32;
            GLDS(A + (size_t)(m0 + row) * K + kt + scol, As + row * 64 + scol);
            GLDS(B + (size_t)(n0 + row) * K + kt + scol, Bs + row * 64 + scol);
        }
        __syncthreads();
#pragma unroll
        for (int kk = 0; kk < 2; ++kk) {
            bf16x8 af[4], bfr[4];
#pragma unroll
            for (int i = 0; i < 4; i++)
                af[i] = *(const bf16x8*)(As + (wr * 64 + i * 16 + lrow) * 64 + kk * 32 + lhi * 8);
#pragma unroll
            for (int j = 0; j < 4; j++)
                bfr[j] = *(const bf16x8*)(Bs + (wc * 64 + j * 16 + lrow) * 64 + kk * 32 + lhi * 8);
#pragma unroll
            for (int i = 0; i < 4; i++)
#pragma unroll
                for (int j = 0; j < 4; j++)
                    acc[i][j] = __builtin_amdgcn_mfma_f32_16x16x32_bf16(af[i], bfr[j], acc[i][j], 0, 0, 0);
        }
    }
#pragma unroll
    for (int i = 0; i < 4; i++)
#pragma unroll
        for (int j = 0; j < 4; j++)
#pragma unroll
            for (int e = 0; e < 4; e++) {
                int row = m0 + wr * 64 + i * 16 + lhi * 4 + e;
                int col = n0 + wc * 64 + j * 16 + lrow;
                if (F32OUT) Cf[(size_t)row * N + col] = acc[i][j][e];
                else        Cb[(size_t)row * N + col] = f2b(acc[i][j][e]);
            }
}

// ---------------------------------------------------------------- RMSNorm + RoPE
// One block per row t. DROW = full row width (2048 for Q, 512 for K).
template<int DROW>
__global__ __launch_bounds__(256) void norm_rope(
    const ushort_t* __restrict__ src, int sld, int scol,
    const float* __restrict__ w,
    const float* __restrict__ cosT, const float* __restrict__ sinT,
    ushort_t* __restrict__ dst, int dld, float oscale)
{
    constexpr int PER = DROW / 256;
    __shared__ float rowbuf[DROW];
    __shared__ float red[4];
    const int tid = threadIdx.x;
    const int t = blockIdx.x;
    const ushort_t* rp = src + (size_t)t * sld + scol;
    const int e0 = tid * PER;

    float vals[PER];
    if constexpr (PER == 8) {
        us8 u = *(const us8*)(rp + e0);
#pragma unroll
        for (int p = 0; p < PER; p++) vals[p] = b2f(u[p]);
    } else {
        ushort2 u = *(const ushort2*)(rp + e0);
        vals[0] = b2f(u.x); vals[1] = b2f(u.y);
    }
    float ss = 0.f;
#pragma unroll
    for (int p = 0; p < PER; p++) { ss += vals[p] * vals[p]; rowbuf[e0 + p] = vals[p]; }
#pragma unroll
    for (int o = 32; o; o >>= 1) ss += __shfl_down(ss, o);
    if ((tid & 63) == 0) red[tid >> 6] = ss;
    __syncthreads();
    float rn = rsqrtf((red[0] + red[1] + red[2] + red[3]) / (float)DROW + 1e-6f);
#pragma unroll
    for (int p = 0; p < PER; p++) {
        int e = e0 + p, r = e & 127;
        float c = cosT[t * HDIM + r], s = sinT[t * HDIM + r];
        int pe = (r < 64) ? e + 64 : e - 64;
        float self = rowbuf[e] * rn * w[e];
        float part = rowbuf[pe] * rn * w[pe];
        float o = (r < 64) ? (self * c - part * s) : (self * c + part * s);
        dst[(size_t)t * dld + e] = f2b(o * oscale);
    }
}

// ---------------------------------------------------------------- flash attention
// grid (T/64, H). 256 threads = 4 waves; wave w owns q-rows [q0+w*16, +16).
__global__ __launch_bounds__(256) void fattn(
    const ushort_t* __restrict__ Q,   // (T, 2048) bf16
    const ushort_t* __restrict__ Kb,  // (T, 512) bf16
    const ushort_t* __restrict__ V,   // (T, vld) bf16, head slice at g*128
    int vld,
    ushort_t* __restrict__ ctx)       // (T, 2048) bf16
{
    __shared__ ushort_t Ks[64 * 128];
    __shared__ ushort_t Vt[128 * 64];
    __shared__ ushort_t Pw[4][16 * 64];
    const int tid = threadIdx.x, lane = tid & 63, wv = tid >> 6;
    const int lrow = lane & 15, lhi = lane >> 4;
    const int h = blockIdx.y, qt = blockIdx.x, g = h >> 2;
    const int q0 = qt * 64;

    bf16x8 qf[4];
    {
        int qr = q0 + wv * 16 + lrow;
#pragma unroll
        for (int ks = 0; ks < 4; ks++)
            qf[ks] = *(const bf16x8*)(Q + (size_t)qr * DMODEL + h * HDIM + ks * 32 + lhi * 8);
    }
    f32x4 of[8];
#pragma unroll
    for (int f = 0; f < 8; f++) of[f] = f32x4{0.f, 0.f, 0.f, 0.f};
    float m_[4], l_[4];
#pragma unroll
    for (int j = 0; j < 4; j++) { m_[j] = -1e30f; l_[j] = 0.f; }
    int myrow[4];
#pragma unroll
    for (int j = 0; j < 4; j++) myrow[j] = q0 + wv * 16 + lhi * 4 + j;

    const int srow = tid >> 4;        // 0..15
    const int scol = (tid & 15) * 8;  // 0..120

    for (int kt = 0; kt <= qt; ++kt) {
        const int k0 = kt * 64;
        __syncthreads();
#pragma unroll
        for (int r = 0; r < 4; r++) {
            int row = srow + r * 16;
            GLDS(Kb + (size_t)(k0 + row) * KVDIM + g * HDIM + scol, Ks + row * 128 + scol);
        }
#pragma unroll
        for (int r = 0; r < 4; r++) {
            int row = srow + r * 16;
            us8 v8 = *(const us8*)(V + (size_t)(k0 + row) * vld + g * HDIM + scol);
#pragma unroll
            for (int x = 0; x < 8; x++) Vt[(scol + x) * 64 + row] = v8[x];
        }
        __syncthreads();

        f32x4 sf[4];
#pragma unroll
        for (int nf = 0; nf < 4; nf++) sf[nf] = f32x4{0.f, 0.f, 0.f, 0.f};
#pragma unroll
        for (int ks = 0; ks < 4; ks++) {
#pragma unroll
            for (int nf = 0; nf < 4; nf++) {
                bf16x8 kf = *(const bf16x8*)(Ks + (nf * 16 + lrow) * 128 + ks * 32 + lhi * 8);
                sf[nf] = __builtin_amdgcn_mfma_f32_16x16x32_bf16(qf[ks], kf, sf[nf], 0, 0, 0);
            }
        }
        // causal mask
#pragma unroll
        for (int nf = 0; nf < 4; nf++) {
            int key = k0 + nf * 16 + lrow;
#pragma unroll
            for (int j = 0; j < 4; j++)
                if (key > myrow[j]) sf[nf][j] = -1e30f;
        }
        // online softmax (row j lives in lanes sharing lhi; reduce across lane&15)
        float pf[4][4], sc[4];
#pragma unroll
        for (int j = 0; j < 4; j++) {
            float mx = fmaxf(fmaxf(sf[0][j], sf[1][j]), fmaxf(sf[2][j], sf[3][j]));
#pragma unroll
            for (int o = 1; o < 16; o <<= 1) mx = fmaxf(mx, __shfl_xor(mx, o));
            float mn = fmaxf(m_[j], mx);
            sc[j] = __expf(m_[j] - mn);
            m_[j] = mn;
        }
#pragma unroll
        for (int nf = 0; nf < 4; nf++)
#pragma unroll
            for (int j = 0; j < 4; j++) pf[nf][j] = __expf(sf[nf][j] - m_[j]);
#pragma unroll
        for (int j = 0; j < 4; j++) {
            float rs = pf[0][j] + pf[1][j] + pf[2][j] + pf[3][j];
#pragma unroll
            for (int o = 1; o < 16; o <<= 1) rs += __shfl_xor(rs, o);
            l_[j] = l_[j] * sc[j] + rs;
        }
#pragma unroll
        for (int f = 0; f < 8; f++)
#pragma unroll
            for (int j = 0; j < 4; j++) of[f][j] *= sc[j];
        // P -> per-wave LDS (C-layout -> A-layout transpose)
#pragma unroll
        for (int nf = 0; nf < 4; nf++)
#pragma unroll
            for (int j = 0; j < 4; j++)
                Pw[wv][(lhi * 4 + j) * 64 + nf * 16 + lrow] = f2b(pf[nf][j]);
        // PV
#pragma unroll
        for (int k2 = 0; k2 < 2; k2++) {
            bf16x8 pa = *(const bf16x8*)(Pw[wv] + lrow * 64 + k2 * 32 + lhi * 8);
#pragma unroll
            for (int f = 0; f < 8; f++) {
                bf16x8 vf = *(const bf16x8*)(Vt + (f * 16 + lrow) * 64 + k2 * 32 + lhi * 8);
                of[f] = __builtin_amdgcn_mfma_f32_16x16x32_bf16(pa, vf, of[f], 0, 0, 0);
            }
        }
    }
#pragma unroll
    for (int f = 0; f < 8; f++)
#pragma unroll
        for (int j = 0; j < 4; j++) {
            float o = of[f][j] / l_[j];
            ctx[(size_t)myrow[j] * DMODEL + h * HDIM + f * 16 + lrow] = f2b(o);
        }
}

// ---------------------------------------------------------------- launch
extern "C" void kernel_launch(void* const* d_in, const int* in_sizes, int n_in,
                              void* d_out, int out_size, void* d_ws, size_t ws_size,
                              hipStream_t stream)
{
    const float* x    = (const float*)d_in[0];
    const float* cosT = (const float*)d_in[2];
    const float* sinT = (const float*)d_in[3];
    const float* Wq   = (const float*)d_in[4];
    const float* Wk   = (const float*)d_in[5];
    const float* Wv   = (const float*)d_in[6];
    const float* Wo   = (const float*)d_in[7];
    const float* qw   = (const float*)d_in[8];
    const float* kw   = (const float*)d_in[9];
    float* out = (float*)d_out;

    char* ws = (char*)d_ws;
    size_t off = 0;
    auto alloc = [&](size_t bytes) -> char* {
        char* p = ws + off; off += (bytes + 255) & ~(size_t)255; return p;
    };
    ushort_t* xb    = (ushort_t*)alloc((size_t)T_SEQ * DMODEL * 2);
    ushort_t* wqkvb = (ushort_t*)alloc((size_t)QKVN * DMODEL * 2);
    ushort_t* wob   = (ushort_t*)alloc((size_t)DMODEL * DMODEL * 2);
    ushort_t* qkvb  = (ushort_t*)alloc((size_t)T_SEQ * QKVN * 2);
    ushort_t* qb    = (ushort_t*)alloc((size_t)T_SEQ * DMODEL * 2);
    ushort_t* kb    = (ushort_t*)alloc((size_t)T_SEQ * KVDIM * 2);
    ushort_t* ctxb  = (ushort_t*)alloc((size_t)T_SEQ * DMODEL * 2);

    auto cvt = [&](const float* s, ushort_t* d, int n) {
        cvt_kernel<<<dim3((n / 4 + 255) / 256), dim3(256), 0, stream>>>(s, d, n);
    };
    cvt(x,  xb, T_SEQ * DMODEL);
    cvt(Wq, wqkvb, DMODEL * DMODEL);
    cvt(Wk, wqkvb + (size_t)DMODEL * DMODEL, KVDIM * DMODEL);
    cvt(Wv, wqkvb + (size_t)(DMODEL + KVDIM) * DMODEL, KVDIM * DMODEL);
    cvt(Wo, wob, DMODEL * DMODEL);

    gemm_bt<false><<<dim3(QKVN / 128, T_SEQ / 128), dim3(256), 0, stream>>>(
        xb, wqkvb, qkvb, nullptr, T_SEQ, QKVN, DMODEL);

    norm_rope<DMODEL><<<dim3(T_SEQ), dim3(256), 0, stream>>>(
        qkvb, QKVN, 0, qw, cosT, sinT, qb, DMODEL, 0.08838834764831843f);
    norm_rope<KVDIM><<<dim3(T_SEQ), dim3(256), 0, stream>>>(
        qkvb, QKVN, DMODEL, kw, cosT, sinT, kb, KVDIM, 1.0f);

    fattn<<<dim3(T_SEQ / 64, NHEADS), dim3(256), 0, stream>>>(
        qb, kb, qkvb + DMODEL + KVDIM, QKVN, ctxb);

    gemm_bt<true><<<dim3(DMODEL / 128, T_SEQ / 128), dim3(256), 0, stream>>>(
        ctxb, wob, nullptr, out, T_SEQ, DMODEL, DMODEL);
}

// Round 4
// 306.241 us; speedup vs baseline: 1.5712x; 1.5712x over previous
//
#include <hip/hip_runtime.h>

#define T_SEQ 2048
#define DMODEL 2048
#define NHEADS 16
#define NKV 4
#define HDIM 128
#define KVDIM (NKV*HDIM)          // 512
#define QKVN (DMODEL + 2*KVDIM)   // 3072

typedef __bf16 bf16x8 __attribute__((ext_vector_type(8)));
typedef float f32x4 __attribute__((ext_vector_type(4)));
typedef unsigned short us8 __attribute__((ext_vector_type(8)));
typedef unsigned short ushort_t;

__device__ __forceinline__ ushort_t f2b(float f) {
    union { float f; unsigned u; } c; c.f = f;
    unsigned r = c.u + 0x7FFFu + ((c.u >> 16) & 1u);
    return (ushort_t)(r >> 16);
}
__device__ __forceinline__ float b2f(ushort_t b) {
    union { unsigned u; float f; } c; c.u = ((unsigned)b) << 16; return c.f;
}

#define GLDS(g, l) __builtin_amdgcn_global_load_lds( \
    (const __attribute__((address_space(1))) void*)(g), \
    (__attribute__((address_space(3))) void*)(l), 16, 0, 0)

// ---------------------------------------------------------------- convert
__global__ __launch_bounds__(256) void cvt_kernel(const float* __restrict__ s,
                                                  ushort_t* __restrict__ d, int n) {
    int i = (blockIdx.x * 256 + threadIdx.x) * 4;
    if (i < n) {
        const float4 v = *(const float4*)(s + i);
        ushort4 o = make_ushort4(f2b(v.x), f2b(v.y), f2b(v.z), f2b(v.w));
        *(ushort4*)(d + i) = o;
    }
}

// ---------------------------------------------------------------- GEMM C = A @ B^T
// A: M x K bf16 row-major, B: N x K bf16 row-major. 128x128 tile, BK=64,
// 256 threads = 4 waves (2x2), each wave 64x64 (4x4 frags of 16x16x32 MFMA).
// MODE 0: bf16 out. MODE 1: f32 out. MODE 2: bf16 out, but V-columns
// (n0 >= 2560) are written TRANSPOSED to VT[512][T_SEQ] instead.
template<int MODE>
__global__ __launch_bounds__(256) void gemm_bt(
    const ushort_t* __restrict__ A, const ushort_t* __restrict__ B,
    ushort_t* __restrict__ Cb, float* __restrict__ Cf, ushort_t* __restrict__ VT,
    int M, int N, int K)
{
    __shared__ ushort_t As[128 * 64];
    __shared__ ushort_t Bs[128 * 64];
    const int tid = threadIdx.x;
    const int lane = tid & 63;
    const int wv = tid >> 6;
    const int wr = wv >> 1, wc = wv & 1;
    const int lrow = lane & 15, lhi = lane >> 4;
    const int m0 = blockIdx.y * 128, n0 = blockIdx.x * 128;

    f32x4 acc[4][4];
#pragma unroll
    for (int i = 0; i < 4; i++)
#pragma unroll
        for (int j = 0; j < 4; j++) acc[i][j] = f32x4{0.f, 0.f, 0.f, 0.f};

    const int srow = tid >> 3;          // 0..31
    const int scol = (tid & 7) * 8;     // 0..56

    for (int kt = 0; kt < K; kt += 64) {
        if (kt) __syncthreads();
#pragma unroll
        for (int r = 0; r < 4; ++r) {
            int row = srow + r * 32;
            GLDS(A + (size_t)(m0 + row) * K + kt + scol, As + row * 64 + scol);
            GLDS(B + (size_t)(n0 + row) * K + kt + scol, Bs + row * 64 + scol);
        }
        __syncthreads();
#pragma unroll
        for (int kk = 0; kk < 2; ++kk) {
            bf16x8 af[4], bfr[4];
#pragma unroll
            for (int i = 0; i < 4; i++)
                af[i] = *(const bf16x8*)(As + (wr * 64 + i * 16 + lrow) * 64 + kk * 32 + lhi * 8);
#pragma unroll
            for (int j = 0; j < 4; j++)
                bfr[j] = *(const bf16x8*)(Bs + (wc * 64 + j * 16 + lrow) * 64 + kk * 32 + lhi * 8);
#pragma unroll
            for (int i = 0; i < 4; i++)
#pragma unroll
                for (int j = 0; j < 4; j++)
                    acc[i][j] = __builtin_amdgcn_mfma_f32_16x16x32_bf16(af[i], bfr[j], acc[i][j], 0, 0, 0);
        }
    }
    if (MODE == 2 && n0 >= DMODEL + KVDIM) {
        // V block: write transposed VT[col][row], 4 consecutive rows pack to 8B
#pragma unroll
        for (int i = 0; i < 4; i++)
#pragma unroll
            for (int j = 0; j < 4; j++) {
                int col = n0 + wc * 64 + j * 16 + lrow - (DMODEL + KVDIM);
                int row0 = m0 + wr * 64 + i * 16 + lhi * 4;
                ushort4 pk = make_ushort4(f2b(acc[i][j][0]), f2b(acc[i][j][1]),
                                          f2b(acc[i][j][2]), f2b(acc[i][j][3]));
                *(ushort4*)(VT + (size_t)col * T_SEQ + row0) = pk;
            }
    } else {
#pragma unroll
        for (int i = 0; i < 4; i++)
#pragma unroll
            for (int j = 0; j < 4; j++)
#pragma unroll
                for (int e = 0; e < 4; e++) {
                    int row = m0 + wr * 64 + i * 16 + lhi * 4 + e;
                    int col = n0 + wc * 64 + j * 16 + lrow;
                    if (MODE == 1) Cf[(size_t)row * N + col] = acc[i][j][e];
                    else           Cb[(size_t)row * N + col] = f2b(acc[i][j][e]);
                }
    }
}

// ---------------------------------------------------------------- RMSNorm + RoPE
template<int DROW>
__global__ __launch_bounds__(256) void norm_rope(
    const ushort_t* __restrict__ src, int sld, int scol,
    const float* __restrict__ w,
    const float* __restrict__ cosT, const float* __restrict__ sinT,
    ushort_t* __restrict__ dst, int dld, float oscale)
{
    constexpr int PER = DROW / 256;
    __shared__ float rowbuf[DROW];
    __shared__ float red[4];
    const int tid = threadIdx.x;
    const int t = blockIdx.x;
    const ushort_t* rp = src + (size_t)t * sld + scol;
    const int e0 = tid * PER;

    float vals[PER];
    if constexpr (PER == 8) {
        us8 u = *(const us8*)(rp + e0);
#pragma unroll
        for (int p = 0; p < PER; p++) vals[p] = b2f(u[p]);
    } else {
        ushort2 u = *(const ushort2*)(rp + e0);
        vals[0] = b2f(u.x); vals[1] = b2f(u.y);
    }
    float ss = 0.f;
#pragma unroll
    for (int p = 0; p < PER; p++) { ss += vals[p] * vals[p]; rowbuf[e0 + p] = vals[p]; }
#pragma unroll
    for (int o = 32; o; o >>= 1) ss += __shfl_down(ss, o);
    if ((tid & 63) == 0) red[tid >> 6] = ss;
    __syncthreads();
    float rn = rsqrtf((red[0] + red[1] + red[2] + red[3]) / (float)DROW + 1e-6f);
#pragma unroll
    for (int p = 0; p < PER; p++) {
        int e = e0 + p, r = e & 127;
        float c = cosT[t * HDIM + r], s = sinT[t * HDIM + r];
        int pe = (r < 64) ? e + 64 : e - 64;
        float self = rowbuf[e] * rn * w[e];
        float part = rowbuf[pe] * rn * w[pe];
        float o = (r < 64) ? (self * c - part * s) : (self * c + part * s);
        dst[(size_t)t * dld + e] = f2b(o * oscale);
    }
}

// ---------------------------------------------------------------- flash attention
// grid (NHEADS, 32). qt = 31 - blockIdx.y (LPT: biggest causal blocks first).
// 256 threads = 4 waves; wave w owns q-rows [q0+w*16, +16).
// K LDS [64][128] and VT LDS [128][64] both XOR-swizzled (16B unit ^= row&7),
// staged via global_load_lds with pre-swizzled global source (rule #21).
// Double-buffered: stage(t+1) issued before compute(t), 1 barrier/tile.
__global__ __launch_bounds__(256) void fattn(
    const ushort_t* __restrict__ Q,   // (T, 2048) bf16 normed+roped+scaled
    const ushort_t* __restrict__ Kb,  // (T, 512) bf16 normed+roped
    const ushort_t* __restrict__ VT,  // (512, T) bf16  (V transposed)
    ushort_t* __restrict__ ctx)       // (T, 2048) bf16
{
    __shared__ ushort_t Ks[2][64 * 128];
    __shared__ ushort_t Vt[2][128 * 64];
    __shared__ ushort_t Pw[4][16 * 64];
    const int tid = threadIdx.x, lane = tid & 63, wv = tid >> 6;
    const int lrow = lane & 15, lhi = lane >> 4;
    const int h = blockIdx.x;
    const int qt = 31 - (int)blockIdx.y;
    const int g = h >> 2;
    const int q0 = qt * 64;

    const int srK = tid >> 4, scK = tid & 15;  // K: 16 rows x 16 units/call
    const int srV = tid >> 3, scV = tid & 7;   // V: 32 rows x 8 units/call

    bf16x8 qf[4];
    {
        int qr = q0 + wv * 16 + lrow;
#pragma unroll
        for (int ks = 0; ks < 4; ks++)
            qf[ks] = *(const bf16x8*)(Q + (size_t)qr * DMODEL + h * HDIM + ks * 32 + lhi * 8);
    }
    f32x4 of[8];
#pragma unroll
    for (int f = 0; f < 8; f++) of[f] = f32x4{0.f, 0.f, 0.f, 0.f};
    float m_[4], l_[4];
#pragma unroll
    for (int j = 0; j < 4; j++) { m_[j] = -1e30f; l_[j] = 0.f; }
    int myrow[4];
#pragma unroll
    for (int j = 0; j < 4; j++) myrow[j] = q0 + wv * 16 + lhi * 4 + j;

    auto stage = [&](int kt, int b) {
        const int k0 = kt * 64;
#pragma unroll
        for (int r = 0; r < 4; r++) {
            int row = srK + r * 16;
            int c = scK ^ (row & 7);
            GLDS(Kb + (size_t)(k0 + row) * KVDIM + g * HDIM + c * 8,
                 Ks[b] + row * 128 + scK * 8);
        }
#pragma unroll
        for (int r = 0; r < 4; r++) {
            int row = srV + r * 32;
            int c = scV ^ (row & 7);
            GLDS(VT + (size_t)(g * HDIM + row) * T_SEQ + k0 + c * 8,
                 Vt[b] + row * 64 + scV * 8);
        }
    };

    stage(0, 0);
    __syncthreads();
    int buf = 0;

    for (int kt = 0; kt <= qt; ++kt) {
        if (kt < qt) stage(kt + 1, buf ^ 1);
        const ushort_t* KsB = Ks[buf];
        const ushort_t* VtB = Vt[buf];
        const int k0 = kt * 64;

        // QK^T (swizzled K reads)
        f32x4 sf[4];
#pragma unroll
        for (int nf = 0; nf < 4; nf++) sf[nf] = f32x4{0.f, 0.f, 0.f, 0.f};
#pragma unroll
        for (int ks = 0; ks < 4; ks++) {
#pragma unroll
            for (int nf = 0; nf < 4; nf++) {
                bf16x8 kf = *(const bf16x8*)(KsB + (nf * 16 + lrow) * 128 +
                                             (((ks * 4 + lhi) ^ (lrow & 7)) << 3));
                sf[nf] = __builtin_amdgcn_mfma_f32_16x16x32_bf16(qf[ks], kf, sf[nf], 0, 0, 0);
            }
        }
        // causal mask
#pragma unroll
        for (int nf = 0; nf < 4; nf++) {
            int key = k0 + nf * 16 + lrow;
#pragma unroll
            for (int j = 0; j < 4; j++)
                if (key > myrow[j]) sf[nf][j] = -1e30f;
        }
        // online softmax (row j lives across 16 lanes sharing lhi)
        float pf[4][4], sc[4];
#pragma unroll
        for (int j = 0; j < 4; j++) {
            float mx = fmaxf(fmaxf(sf[0][j], sf[1][j]), fmaxf(sf[2][j], sf[3][j]));
#pragma unroll
            for (int o = 1; o < 16; o <<= 1) mx = fmaxf(mx, __shfl_xor(mx, o));
            float mn = fmaxf(m_[j], mx);
            sc[j] = __expf(m_[j] - mn);
            m_[j] = mn;
        }
#pragma unroll
        for (int nf = 0; nf < 4; nf++)
#pragma unroll
            for (int j = 0; j < 4; j++) pf[nf][j] = __expf(sf[nf][j] - m_[j]);
#pragma unroll
        for (int j = 0; j < 4; j++) {
            float rs = pf[0][j] + pf[1][j] + pf[2][j] + pf[3][j];
#pragma unroll
            for (int o = 1; o < 16; o <<= 1) rs += __shfl_xor(rs, o);
            l_[j] = l_[j] * sc[j] + rs;
        }
#pragma unroll
        for (int f = 0; f < 8; f++)
#pragma unroll
            for (int j = 0; j < 4; j++) of[f][j] *= sc[j];
        // P -> per-wave LDS (swizzled write; same-wave read needs no barrier)
#pragma unroll
        for (int nf = 0; nf < 4; nf++)
#pragma unroll
            for (int j = 0; j < 4; j++) {
                int q = lhi * 4 + j;
                int cb = (nf * 16 + lrow) * 2;
                int cbp = cb ^ ((q & 7) << 4);
                Pw[wv][q * 64 + (cbp >> 1)] = f2b(pf[nf][j]);
            }
        // PV (swizzled P + VT reads)
#pragma unroll
        for (int k2 = 0; k2 < 2; k2++) {
            bf16x8 pa = *(const bf16x8*)(Pw[wv] + lrow * 64 +
                                         (((k2 * 4 + lhi) ^ (lrow & 7)) << 3));
#pragma unroll
            for (int f = 0; f < 8; f++) {
                bf16x8 vf = *(const bf16x8*)(VtB + (f * 16 + lrow) * 64 +
                                             (((k2 * 4 + lhi) ^ (lrow & 7)) << 3));
                of[f] = __builtin_amdgcn_mfma_f32_16x16x32_bf16(pa, vf, of[f], 0, 0, 0);
            }
        }
        __syncthreads();   // next tile staged + all waves done with buf
        buf ^= 1;
    }
#pragma unroll
    for (int f = 0; f < 8; f++)
#pragma unroll
        for (int j = 0; j < 4; j++) {
            float o = of[f][j] / l_[j];
            ctx[(size_t)myrow[j] * DMODEL + h * HDIM + f * 16 + lrow] = f2b(o);
        }
}

// ---------------------------------------------------------------- launch
extern "C" void kernel_launch(void* const* d_in, const int* in_sizes, int n_in,
                              void* d_out, int out_size, void* d_ws, size_t ws_size,
                              hipStream_t stream)
{
    const float* x    = (const float*)d_in[0];
    const float* cosT = (const float*)d_in[2];
    const float* sinT = (const float*)d_in[3];
    const float* Wq   = (const float*)d_in[4];
    const float* Wk   = (const float*)d_in[5];
    const float* Wv   = (const float*)d_in[6];
    const float* Wo   = (const float*)d_in[7];
    const float* qw   = (const float*)d_in[8];
    const float* kw   = (const float*)d_in[9];
    float* out = (float*)d_out;

    char* ws = (char*)d_ws;
    size_t off = 0;
    auto alloc = [&](size_t bytes) -> char* {
        char* p = ws + off; off += (bytes + 255) & ~(size_t)255; return p;
    };
    ushort_t* xb    = (ushort_t*)alloc((size_t)T_SEQ * DMODEL * 2);
    ushort_t* wqkvb = (ushort_t*)alloc((size_t)QKVN * DMODEL * 2);
    ushort_t* wob   = (ushort_t*)alloc((size_t)DMODEL * DMODEL * 2);
    ushort_t* qkvb  = (ushort_t*)alloc((size_t)T_SEQ * QKVN * 2);
    ushort_t* qb    = (ushort_t*)alloc((size_t)T_SEQ * DMODEL * 2);
    ushort_t* kb    = (ushort_t*)alloc((size_t)T_SEQ * KVDIM * 2);
    ushort_t* ctxb  = (ushort_t*)alloc((size_t)T_SEQ * DMODEL * 2);
    ushort_t* vtb   = (ushort_t*)alloc((size_t)KVDIM * T_SEQ * 2);

    auto cvt = [&](const float* s, ushort_t* d, int n) {
        cvt_kernel<<<dim3((n / 4 + 255) / 256), dim3(256), 0, stream>>>(s, d, n);
    };
    cvt(x,  xb, T_SEQ * DMODEL);
    cvt(Wq, wqkvb, DMODEL * DMODEL);
    cvt(Wk, wqkvb + (size_t)DMODEL * DMODEL, KVDIM * DMODEL);
    cvt(Wv, wqkvb + (size_t)(DMODEL + KVDIM) * DMODEL, KVDIM * DMODEL);
    cvt(Wo, wob, DMODEL * DMODEL);

    gemm_bt<2><<<dim3(QKVN / 128, T_SEQ / 128), dim3(256), 0, stream>>>(
        xb, wqkvb, qkvb, nullptr, vtb, T_SEQ, QKVN, DMODEL);

    norm_rope<DMODEL><<<dim3(T_SEQ), dim3(256), 0, stream>>>(
        qkvb, QKVN, 0, qw, cosT, sinT, qb, DMODEL, 0.08838834764831843f);
    norm_rope<KVDIM><<<dim3(T_SEQ), dim3(256), 0, stream>>>(
        qkvb, QKVN, DMODEL, kw, cosT, sinT, kb, KVDIM, 1.0f);

    fattn<<<dim3(NHEADS, 32), dim3(256), 0, stream>>>(qb, kb, vtb, ctxb);

    gemm_bt<1><<<dim3(DMODEL / 128, T_SEQ / 128), dim3(256), 0, stream>>>(
        ctxb, wob, nullptr, out, nullptr, T_SEQ, DMODEL, DMODEL);
}

// Round 5
// 292.324 us; speedup vs baseline: 1.6460x; 1.0476x over previous
//
#include <hip/hip_runtime.h>

#define T_SEQ 2048
#define DMODEL 2048
#define NHEADS 16
#define NKV 4
#define HDIM 128
#define KVDIM (NKV*HDIM)          // 512
#define QKVN (DMODEL + 2*KVDIM)   // 3072

typedef __bf16 bf16x8 __attribute__((ext_vector_type(8)));
typedef float f32x4 __attribute__((ext_vector_type(4)));
typedef unsigned short us8 __attribute__((ext_vector_type(8)));
typedef unsigned short ushort_t;

__device__ __forceinline__ ushort_t f2b(float f) {
    union { float f; unsigned u; } c; c.f = f;
    unsigned r = c.u + 0x7FFFu + ((c.u >> 16) & 1u);
    return (ushort_t)(r >> 16);
}
__device__ __forceinline__ ushort_t f2b_rn(float f) {   // native cvt (RTNE), hot path
    union { __bf16 h; ushort_t u; } c; c.h = (__bf16)f; return c.u;
}
__device__ __forceinline__ float b2f(ushort_t b) {
    union { unsigned u; float f; } c; c.u = ((unsigned)b) << 16; return c.f;
}

#define GLDS(g, l) __builtin_amdgcn_global_load_lds( \
    (const __attribute__((address_space(1))) void*)(g), \
    (__attribute__((address_space(3))) void*)(l), 16, 0, 0)

// ---------------------------------------------------------------- convert (all 5 tensors, 1 launch)
__global__ __launch_bounds__(256) void cvt5_kernel(
    const float* __restrict__ s0, ushort_t* __restrict__ d0, int c0,
    const float* __restrict__ s1, ushort_t* __restrict__ d1, int c1,
    const float* __restrict__ s2, ushort_t* __restrict__ d2, int c2,
    const float* __restrict__ s3, ushort_t* __restrict__ d3, int c3,
    const float* __restrict__ s4, ushort_t* __restrict__ d4, int c4)
{
    int u = blockIdx.x * 256 + threadIdx.x;   // float4 index
    const float* s; ushort_t* d; int off;
    if      (u < c0) { s = s0; d = d0; off = u; }
    else if (u < c1) { s = s1; d = d1; off = u - c0; }
    else if (u < c2) { s = s2; d = d2; off = u - c1; }
    else if (u < c3) { s = s3; d = d3; off = u - c2; }
    else if (u < c4) { s = s4; d = d4; off = u - c3; }
    else return;
    const float4 v = *(const float4*)(s + off * 4);
    ushort4 o = make_ushort4(f2b(v.x), f2b(v.y), f2b(v.z), f2b(v.w));
    *(ushort4*)(d + off * 4) = o;
}

// ---------------------------------------------------------------- GEMM C = A @ B^T
// A: M x K bf16 row-major, B: N x K bf16 row-major. 128x128 tile, BK=64,
// 256 threads = 4 waves (2x2), each wave 64x64 (4x4 frags of 16x16x32 MFMA).
// MODE 1: f32 out. MODE 2: bf16 out, V-columns (n0 >= 2560) transposed to VT.
template<int MODE>
__global__ __launch_bounds__(256) void gemm_bt(
    const ushort_t* __restrict__ A, const ushort_t* __restrict__ B,
    ushort_t* __restrict__ Cb, float* __restrict__ Cf, ushort_t* __restrict__ VT,
    int M, int N, int K)
{
    __shared__ ushort_t As[128 * 64];
    __shared__ ushort_t Bs[128 * 64];
    const int tid = threadIdx.x;
    const int lane = tid & 63;
    const int wv = tid >> 6;
    const int wr = wv >> 1, wc = wv & 1;
    const int lrow = lane & 15, lhi = lane >> 4;
    const int m0 = blockIdx.y * 128, n0 = blockIdx.x * 128;

    f32x4 acc[4][4];
#pragma unroll
    for (int i = 0; i < 4; i++)
#pragma unroll
        for (int j = 0; j < 4; j++) acc[i][j] = f32x4{0.f, 0.f, 0.f, 0.f};

    const int srow = tid >> 3;          // 0..31
    const int scol = (tid & 7) * 8;     // 0..56

    for (int kt = 0; kt < K; kt += 64) {
        if (kt) __syncthreads();
#pragma unroll
        for (int r = 0; r < 4; ++r) {
            int row = srow + r * 32;
            GLDS(A + (size_t)(m0 + row) * K + kt + scol, As + row * 64 + scol);
            GLDS(B + (size_t)(n0 + row) * K + kt + scol, Bs + row * 64 + scol);
        }
        __syncthreads();
#pragma unroll
        for (int kk = 0; kk < 2; ++kk) {
            bf16x8 af[4], bfr[4];
#pragma unroll
            for (int i = 0; i < 4; i++)
                af[i] = *(const bf16x8*)(As + (wr * 64 + i * 16 + lrow) * 64 + kk * 32 + lhi * 8);
#pragma unroll
            for (int j = 0; j < 4; j++)
                bfr[j] = *(const bf16x8*)(Bs + (wc * 64 + j * 16 + lrow) * 64 + kk * 32 + lhi * 8);
#pragma unroll
            for (int i = 0; i < 4; i++)
#pragma unroll
                for (int j = 0; j < 4; j++)
                    acc[i][j] = __builtin_amdgcn_mfma_f32_16x16x32_bf16(af[i], bfr[j], acc[i][j], 0, 0, 0);
        }
    }
    if (MODE == 2 && n0 >= DMODEL + KVDIM) {
        // V block: write transposed VT[col][row], 4 consecutive rows pack to 8B
#pragma unroll
        for (int i = 0; i < 4; i++)
#pragma unroll
            for (int j = 0; j < 4; j++) {
                int col = n0 + wc * 64 + j * 16 + lrow - (DMODEL + KVDIM);
                int row0 = m0 + wr * 64 + i * 16 + lhi * 4;
                ushort4 pk = make_ushort4(f2b(acc[i][j][0]), f2b(acc[i][j][1]),
                                          f2b(acc[i][j][2]), f2b(acc[i][j][3]));
                *(ushort4*)(VT + (size_t)col * T_SEQ + row0) = pk;
            }
    } else {
#pragma unroll
        for (int i = 0; i < 4; i++)
#pragma unroll
            for (int j = 0; j < 4; j++)
#pragma unroll
                for (int e = 0; e < 4; e++) {
                    int row = m0 + wr * 64 + i * 16 + lhi * 4 + e;
                    int col = n0 + wc * 64 + j * 16 + lrow;
                    if (MODE == 1) Cf[(size_t)row * N + col] = acc[i][j][e];
                    else           Cb[(size_t)row * N + col] = f2b(acc[i][j][e]);
                }
    }
}

// ---------------------------------------------------------------- RMSNorm + RoPE (Q and K in one launch)
template<int DROW>
__device__ __forceinline__ void norm_rope_body(
    const ushort_t* __restrict__ src, int sld, int scol,
    const float* __restrict__ w,
    const float* __restrict__ cosT, const float* __restrict__ sinT,
    ushort_t* __restrict__ dst, int dld, float oscale,
    float* rowbuf, float* red)
{
    constexpr int PER = DROW / 256;
    const int tid = threadIdx.x;
    const int t = blockIdx.x;
    const ushort_t* rp = src + (size_t)t * sld + scol;
    const int e0 = tid * PER;

    float vals[PER];
    if constexpr (PER == 8) {
        us8 u = *(const us8*)(rp + e0);
#pragma unroll
        for (int p = 0; p < PER; p++) vals[p] = b2f(u[p]);
    } else {
        ushort2 u = *(const ushort2*)(rp + e0);
        vals[0] = b2f(u.x); vals[1] = b2f(u.y);
    }
    float ss = 0.f;
#pragma unroll
    for (int p = 0; p < PER; p++) { ss += vals[p] * vals[p]; rowbuf[e0 + p] = vals[p]; }
#pragma unroll
    for (int o = 32; o; o >>= 1) ss += __shfl_down(ss, o);
    if ((tid & 63) == 0) red[tid >> 6] = ss;
    __syncthreads();
    float rn = rsqrtf((red[0] + red[1] + red[2] + red[3]) / (float)DROW + 1e-6f);
#pragma unroll
    for (int p = 0; p < PER; p++) {
        int e = e0 + p, r = e & 127;
        float c = cosT[t * HDIM + r], s = sinT[t * HDIM + r];
        int pe = (r < 64) ? e + 64 : e - 64;
        float self = rowbuf[e] * rn * w[e];
        float part = rowbuf[pe] * rn * w[pe];
        float o = (r < 64) ? (self * c - part * s) : (self * c + part * s);
        dst[(size_t)t * dld + e] = f2b(o * oscale);
    }
}

__global__ __launch_bounds__(256) void norm_rope_qk(
    const ushort_t* __restrict__ qkv,
    const float* __restrict__ qw, const float* __restrict__ kw,
    const float* __restrict__ cosT, const float* __restrict__ sinT,
    ushort_t* __restrict__ qb, ushort_t* __restrict__ kb)
{
    __shared__ float rowbuf[DMODEL];
    __shared__ float red[4];
    if (blockIdx.y == 0)
        norm_rope_body<DMODEL>(qkv, QKVN, 0, qw, cosT, sinT, qb, DMODEL,
                               0.08838834764831843f, rowbuf, red);
    else
        norm_rope_body<KVDIM>(qkv, QKVN, DMODEL, kw, cosT, sinT, kb, KVDIM,
                              1.0f, rowbuf, red);
}

// ---------------------------------------------------------------- flash attention
// grid (NHEADS, 32). qt = 31 - blockIdx.y (LPT). 4 waves; wave w owns 16 q-rows.
// K/V XOR-swizzled LDS (rule #21: pre-swizzled global src + swizzled reads),
// double-buffered, 1 barrier/tile. Defer-max (T13), per-lane partial l.
__global__ __launch_bounds__(256) void fattn(
    const ushort_t* __restrict__ Q,   // (T, 2048) bf16 normed+roped+scaled
    const ushort_t* __restrict__ Kb,  // (T, 512) bf16 normed+roped
    const ushort_t* __restrict__ VT,  // (512, T) bf16  (V transposed)
    ushort_t* __restrict__ ctx)       // (T, 2048) bf16
{
    __shared__ ushort_t Ks[2][64 * 128];
    __shared__ ushort_t Vt[2][128 * 64];
    __shared__ ushort_t Pw[4][16 * 64];
    const int tid = threadIdx.x, lane = tid & 63, wv = tid >> 6;
    const int lrow = lane & 15, lhi = lane >> 4;
    const int h = blockIdx.x;
    const int qt = 31 - (int)blockIdx.y;
    const int g = h >> 2;
    const int q0 = qt * 64;

    const int srK = tid >> 4, scK = tid & 15;  // K: 16 rows x 16 units/call
    const int srV = tid >> 3, scV = tid & 7;   // V: 32 rows x 8 units/call

    bf16x8 qf[4];
    {
        int qr = q0 + wv * 16 + lrow;
#pragma unroll
        for (int ks = 0; ks < 4; ks++)
            qf[ks] = *(const bf16x8*)(Q + (size_t)qr * DMODEL + h * HDIM + ks * 32 + lhi * 8);
    }
    f32x4 of[8];
#pragma unroll
    for (int f = 0; f < 8; f++) of[f] = f32x4{0.f, 0.f, 0.f, 0.f};
    float m_[4], l_[4];   // l_ is a PER-LANE partial (reduced once at the end)
#pragma unroll
    for (int j = 0; j < 4; j++) { m_[j] = -1e30f; l_[j] = 0.f; }
    int myrow[4];
#pragma unroll
    for (int j = 0; j < 4; j++) myrow[j] = q0 + wv * 16 + lhi * 4 + j;

    auto stage = [&](int kt, int b) {
        const int k0 = kt * 64;
#pragma unroll
        for (int r = 0; r < 4; r++) {
            int row = srK + r * 16;
            int c = scK ^ (row & 7);
            GLDS(Kb + (size_t)(k0 + row) * KVDIM + g * HDIM + c * 8,
                 Ks[b] + row * 128 + scK * 8);
        }
#pragma unroll
        for (int r = 0; r < 4; r++) {
            int row = srV + r * 32;
            int c = scV ^ (row & 7);
            GLDS(VT + (size_t)(g * HDIM + row) * T_SEQ + k0 + c * 8,
                 Vt[b] + row * 64 + scV * 8);
        }
    };

    stage(0, 0);
    __syncthreads();
    int buf = 0;

    for (int kt = 0; kt <= qt; ++kt) {
        if (kt < qt) stage(kt + 1, buf ^ 1);
        const ushort_t* KsB = Ks[buf];
        const ushort_t* VtB = Vt[buf];
        const int k0 = kt * 64;

        // QK^T (swizzled K reads)
        f32x4 sf[4];
#pragma unroll
        for (int nf = 0; nf < 4; nf++) sf[nf] = f32x4{0.f, 0.f, 0.f, 0.f};
#pragma unroll
        for (int ks = 0; ks < 4; ks++) {
#pragma unroll
            for (int nf = 0; nf < 4; nf++) {
                bf16x8 kf = *(const bf16x8*)(KsB + (nf * 16 + lrow) * 128 +
                                             (((ks * 4 + lhi) ^ (lrow & 7)) << 3));
                sf[nf] = __builtin_amdgcn_mfma_f32_16x16x32_bf16(qf[ks], kf, sf[nf], 0, 0, 0);
            }
        }
        // causal mask
#pragma unroll
        for (int nf = 0; nf < 4; nf++) {
            int key = k0 + nf * 16 + lrow;
#pragma unroll
            for (int j = 0; j < 4; j++)
                if (key > myrow[j]) sf[nf][j] = -1e30f;
        }
        // row max (16-lane reduce)
        float mx[4];
#pragma unroll
        for (int j = 0; j < 4; j++) {
            float m2 = fmaxf(fmaxf(sf[0][j], sf[1][j]), fmaxf(sf[2][j], sf[3][j]));
#pragma unroll
            for (int o = 1; o < 16; o <<= 1) m2 = fmaxf(m2, __shfl_xor(m2, o));
            mx[j] = m2;
        }
        // defer-max (T13): rescale only if some row grew by > 8
        float need = fmaxf(fmaxf(mx[0] - m_[0], mx[1] - m_[1]),
                           fmaxf(mx[2] - m_[2], mx[3] - m_[3]));
        if (!__all(need <= 8.0f)) {
#pragma unroll
            for (int j = 0; j < 4; j++) {
                float mn = fmaxf(m_[j], mx[j]);
                float sc = __expf(m_[j] - mn);
                m_[j] = mn;
                l_[j] *= sc;
#pragma unroll
                for (int f = 0; f < 8; f++) of[f][j] *= sc;
            }
        }
        // P = exp(S - m), per-lane partial l
        float pf[4][4];
#pragma unroll
        for (int nf = 0; nf < 4; nf++)
#pragma unroll
            for (int j = 0; j < 4; j++) pf[nf][j] = __expf(sf[nf][j] - m_[j]);
#pragma unroll
        for (int j = 0; j < 4; j++)
            l_[j] += (pf[0][j] + pf[1][j]) + (pf[2][j] + pf[3][j]);
        // P -> per-wave LDS (swizzled write; same-wave read needs no barrier)
#pragma unroll
        for (int nf = 0; nf < 4; nf++)
#pragma unroll
            for (int j = 0; j < 4; j++) {
                int q = lhi * 4 + j;
                int cb = (nf * 16 + lrow) * 2;
                int cbp = cb ^ ((q & 7) << 4);
                Pw[wv][q * 64 + (cbp >> 1)] = f2b_rn(pf[nf][j]);
            }
        // PV (swizzled P + VT reads)
#pragma unroll
        for (int k2 = 0; k2 < 2; k2++) {
            bf16x8 pa = *(const bf16x8*)(Pw[wv] + lrow * 64 +
                                         (((k2 * 4 + lhi) ^ (lrow & 7)) << 3));
#pragma unroll
            for (int f = 0; f < 8; f++) {
                bf16x8 vf = *(const bf16x8*)(VtB + (f * 16 + lrow) * 64 +
                                             (((k2 * 4 + lhi) ^ (lrow & 7)) << 3));
                of[f] = __builtin_amdgcn_mfma_f32_16x16x32_bf16(pa, vf, of[f], 0, 0, 0);
            }
        }
        __syncthreads();   // next tile staged + all waves done with buf
        buf ^= 1;
    }
    // final l reduce (was per-tile; rescales commute with the partial sum)
#pragma unroll
    for (int j = 0; j < 4; j++) {
#pragma unroll
        for (int o = 1; o < 16; o <<= 1) l_[j] += __shfl_xor(l_[j], o);
    }
#pragma unroll
    for (int f = 0; f < 8; f++)
#pragma unroll
        for (int j = 0; j < 4; j++) {
            float o = of[f][j] / l_[j];
            ctx[(size_t)myrow[j] * DMODEL + h * HDIM + f * 16 + lrow] = f2b_rn(o);
        }
}

// ---------------------------------------------------------------- launch
extern "C" void kernel_launch(void* const* d_in, const int* in_sizes, int n_in,
                              void* d_out, int out_size, void* d_ws, size_t ws_size,
                              hipStream_t stream)
{
    const float* x    = (const float*)d_in[0];
    const float* cosT = (const float*)d_in[2];
    const float* sinT = (const float*)d_in[3];
    const float* Wq   = (const float*)d_in[4];
    const float* Wk   = (const float*)d_in[5];
    const float* Wv   = (const float*)d_in[6];
    const float* Wo   = (const float*)d_in[7];
    const float* qw   = (const float*)d_in[8];
    const float* kw   = (const float*)d_in[9];
    float* out = (float*)d_out;

    char* ws = (char*)d_ws;
    size_t off = 0;
    auto alloc = [&](size_t bytes) -> char* {
        char* p = ws + off; off += (bytes + 255) & ~(size_t)255; return p;
    };
    ushort_t* xb    = (ushort_t*)alloc((size_t)T_SEQ * DMODEL * 2);
    ushort_t* wqkvb = (ushort_t*)alloc((size_t)QKVN * DMODEL * 2);
    ushort_t* wob   = (ushort_t*)alloc((size_t)DMODEL * DMODEL * 2);
    ushort_t* qkvb  = (ushort_t*)alloc((size_t)T_SEQ * QKVN * 2);
    ushort_t* qb    = (ushort_t*)alloc((size_t)T_SEQ * DMODEL * 2);
    ushort_t* kb    = (ushort_t*)alloc((size_t)T_SEQ * KVDIM * 2);
    ushort_t* ctxb  = (ushort_t*)alloc((size_t)T_SEQ * DMODEL * 2);
    ushort_t* vtb   = (ushort_t*)alloc((size_t)KVDIM * T_SEQ * 2);

    // one cvt launch for all five tensors (float4 units, cumulative bounds)
    const int n_x  = T_SEQ * DMODEL / 4;          // 1048576
    const int n_wq = DMODEL * DMODEL / 4;         // 1048576
    const int n_wk = KVDIM * DMODEL / 4;          // 262144
    const int n_wv = KVDIM * DMODEL / 4;          // 262144
    const int n_wo = DMODEL * DMODEL / 4;         // 1048576
    const int c0 = n_x, c1 = c0 + n_wq, c2 = c1 + n_wk, c3 = c2 + n_wv, c4 = c3 + n_wo;
    cvt5_kernel<<<dim3((c4 + 255) / 256), dim3(256), 0, stream>>>(
        x,  xb, c0,
        Wq, wqkvb, c1,
        Wk, wqkvb + (size_t)DMODEL * DMODEL, c2,
        Wv, wqkvb + (size_t)(DMODEL + KVDIM) * DMODEL, c3,
        Wo, wob, c4);

    gemm_bt<2><<<dim3(QKVN / 128, T_SEQ / 128), dim3(256), 0, stream>>>(
        xb, wqkvb, qkvb, nullptr, vtb, T_SEQ, QKVN, DMODEL);

    norm_rope_qk<<<dim3(T_SEQ, 2), dim3(256), 0, stream>>>(
        qkvb, qw, kw, cosT, sinT, qb, kb);

    fattn<<<dim3(NHEADS, 32), dim3(256), 0, stream>>>(qb, kb, vtb, ctxb);

    gemm_bt<1><<<dim3(DMODEL / 128, T_SEQ / 128), dim3(256), 0, stream>>>(
        ctxb, wob, nullptr, out, nullptr, T_SEQ, DMODEL, DMODEL);
}